// Round 1
// baseline (637.043 us; speedup 1.0000x reference)
//
#include <hip/hip_runtime.h>

// Problem constants (B=4, Hs=Ws=256, C=128, n_heads=4, head_dim=32)
#define BATCH 4
#define HW 65536          // Hs*Ws positions per batch
#define CH 128            // channels
#define NHEADS 4
#define HDIM 32
#define EPS 1e-5f
#define INV_NP (1.0f / 65536.0f)
#define INV_C (1.0f / 128.0f)

// ---------------------------------------------------------------------------
// Kernel 1: for a strip of positions, compute k = X@Wk, v = X@Wv (fp32 GEMM,
// register-tiled 4x4 per thread), LayerNorm both over the 128 channels
// (gamma_k/beta_k applied to BOTH, faithful to reference), accumulate the
// per-head outer products kv[h][d][e] in registers across 4 tiles of 32
// positions, then atomicAdd into the global kv accumulator.
//
// grid = 2048 (512 blocks/batch), block = 256.
// Each block: 4 tiles x 32 positions = 128 positions.
// ---------------------------------------------------------------------------
__global__ __launch_bounds__(256) void kv_kernel(const float* __restrict__ X,
                                                 const float* __restrict__ Wk,
                                                 const float* __restrict__ Wv,
                                                 const float* __restrict__ gamma,
                                                 const float* __restrict__ beta,
                                                 float* __restrict__ kv_g) {
    __shared__ float smem[12288];      // 48 KB
    float* Xs  = smem;                 // [32][128] X tile
    float* Wks = smem + 4096;          // [32][128] Wk chunk (rows c0..c0+31)
    float* Wvs = smem + 8192;          // [32][128] Wv chunk
    float* ksm = smem;                 // phase B: normalized k [32][128]
    float* vsm = smem + 4096;          // phase B: normalized v [32][128]

    const int tid = threadIdx.x;
    const int tx = tid & 31;           // channel group: och = tx*4 .. tx*4+3
    const int ty = tid >> 5;           // position group: p = ty*4 .. ty*4+3
    const int b = blockIdx.x >> 9;     // 512 blocks per batch
    const int tile0 = (blockIdx.x & 511) * 4;

    // outer-product assignment: head h, d-tile dt (4 d's), e-tile et (4 e's)
    const int h  = tid >> 6;
    const int idx = tid & 63;
    const int et = idx & 7;
    const int dt = idx >> 3;

    float kvacc[16];
#pragma unroll
    for (int n = 0; n < 16; ++n) kvacc[n] = 0.f;

    float g4[4], be4[4];
#pragma unroll
    for (int j = 0; j < 4; ++j) { g4[j] = gamma[tx * 4 + j]; be4[j] = beta[tx * 4 + j]; }

    for (int g = 0; g < 4; ++g) {
        const int ptile = (tile0 + g) * 32;   // position base within batch
        const float* Xp = X + ((size_t)b * HW + ptile) * CH;

        __syncthreads();   // previous iteration's phase-B LDS reads done
        // stage X tile: 4096 floats, coalesced float4
#pragma unroll
        for (int n = 0; n < 4; ++n) {
            const int i4 = tid + n * 256;
            ((float4*)Xs)[i4] = ((const float4*)Xp)[i4];
        }

        float kacc[16], vacc[16];
#pragma unroll
        for (int n = 0; n < 16; ++n) { kacc[n] = 0.f; vacc[n] = 0.f; }

        for (int c0 = 0; c0 < CH; c0 += 32) {
            __syncthreads();   // previous chunk's reads done (also covers Xs staging)
#pragma unroll
            for (int n = 0; n < 4; ++n) {
                const int i4 = tid + n * 256;
                ((float4*)Wks)[i4] = ((const float4*)(Wk + c0 * CH))[i4];
                ((float4*)Wvs)[i4] = ((const float4*)(Wv + c0 * CH))[i4];
            }
            __syncthreads();
#pragma unroll
            for (int c = 0; c < 32; ++c) {
                const float4 wk4 = *(const float4*)&Wks[c * CH + tx * 4];
                const float4 wv4 = *(const float4*)&Wvs[c * CH + tx * 4];
#pragma unroll
                for (int i = 0; i < 4; ++i) {
                    const float xi = Xs[(ty * 4 + i) * CH + c0 + c];
                    kacc[i * 4 + 0] += xi * wk4.x;
                    kacc[i * 4 + 1] += xi * wk4.y;
                    kacc[i * 4 + 2] += xi * wk4.z;
                    kacc[i * 4 + 3] += xi * wk4.w;
                    vacc[i * 4 + 0] += xi * wv4.x;
                    vacc[i * 4 + 1] += xi * wv4.y;
                    vacc[i * 4 + 2] += xi * wv4.z;
                    vacc[i * 4 + 3] += xi * wv4.w;
                }
            }
        }

        // LayerNorm stats: reduce each position's sum / sumsq over 128 channels.
        // Thread holds 4 channels for 4 positions; reduce across the 32 tx
        // lanes (lower 5 lane bits) via shfl_xor.
        float muk[4], rsk[4], muv[4], rsv[4];
#pragma unroll
        for (int i = 0; i < 4; ++i) {
            float sk = kacc[i * 4] + kacc[i * 4 + 1] + kacc[i * 4 + 2] + kacc[i * 4 + 3];
            float ssk = kacc[i * 4] * kacc[i * 4] + kacc[i * 4 + 1] * kacc[i * 4 + 1]
                      + kacc[i * 4 + 2] * kacc[i * 4 + 2] + kacc[i * 4 + 3] * kacc[i * 4 + 3];
            float sv = vacc[i * 4] + vacc[i * 4 + 1] + vacc[i * 4 + 2] + vacc[i * 4 + 3];
            float ssv = vacc[i * 4] * vacc[i * 4] + vacc[i * 4 + 1] * vacc[i * 4 + 1]
                      + vacc[i * 4 + 2] * vacc[i * 4 + 2] + vacc[i * 4 + 3] * vacc[i * 4 + 3];
#pragma unroll
            for (int m = 1; m <= 16; m <<= 1) {
                sk  += __shfl_xor(sk, m);
                ssk += __shfl_xor(ssk, m);
                sv  += __shfl_xor(sv, m);
                ssv += __shfl_xor(ssv, m);
            }
            const float mk = sk * INV_C;
            const float vk = ssk * INV_C - mk * mk;
            const float mv = sv * INV_C;
            const float vv = ssv * INV_C - mv * mv;
            muk[i] = mk; rsk[i] = 1.0f / sqrtf(vk + EPS);
            muv[i] = mv; rsv[i] = 1.0f / sqrtf(vv + EPS);
        }

        __syncthreads();   // GEMM-phase LDS reads done; reuse smem
#pragma unroll
        for (int i = 0; i < 4; ++i) {
            float4 kn, vn;
            kn.x = (kacc[i * 4 + 0] - muk[i]) * rsk[i] * g4[0] + be4[0];
            kn.y = (kacc[i * 4 + 1] - muk[i]) * rsk[i] * g4[1] + be4[1];
            kn.z = (kacc[i * 4 + 2] - muk[i]) * rsk[i] * g4[2] + be4[2];
            kn.w = (kacc[i * 4 + 3] - muk[i]) * rsk[i] * g4[3] + be4[3];
            vn.x = (vacc[i * 4 + 0] - muv[i]) * rsv[i] * g4[0] + be4[0];
            vn.y = (vacc[i * 4 + 1] - muv[i]) * rsv[i] * g4[1] + be4[1];
            vn.z = (vacc[i * 4 + 2] - muv[i]) * rsv[i] * g4[2] + be4[2];
            vn.w = (vacc[i * 4 + 3] - muv[i]) * rsv[i] * g4[3] + be4[3];
            *(float4*)&ksm[(ty * 4 + i) * CH + tx * 4] = kn;
            *(float4*)&vsm[(ty * 4 + i) * CH + tx * 4] = vn;
        }
        __syncthreads();

        // accumulate kv[h][dt*4+i][et*4+j] over the 32 positions of this tile
#pragma unroll 8
        for (int p = 0; p < 32; ++p) {
            const float4 kd = *(const float4*)&ksm[p * CH + h * HDIM + dt * 4];
            const float4 ve = *(const float4*)&vsm[p * CH + h * HDIM + et * 4];
            kvacc[0]  += kd.x * ve.x; kvacc[1]  += kd.x * ve.y;
            kvacc[2]  += kd.x * ve.z; kvacc[3]  += kd.x * ve.w;
            kvacc[4]  += kd.y * ve.x; kvacc[5]  += kd.y * ve.y;
            kvacc[6]  += kd.y * ve.z; kvacc[7]  += kd.y * ve.w;
            kvacc[8]  += kd.z * ve.x; kvacc[9]  += kd.z * ve.y;
            kvacc[10] += kd.z * ve.z; kvacc[11] += kd.z * ve.w;
            kvacc[12] += kd.w * ve.x; kvacc[13] += kd.w * ve.y;
            kvacc[14] += kd.w * ve.z; kvacc[15] += kd.w * ve.w;
        }
    }

    float* dst = kv_g + b * (NHEADS * HDIM * HDIM) + h * (HDIM * HDIM);
#pragma unroll
    for (int i = 0; i < 4; ++i)
#pragma unroll
        for (int j = 0; j < 4; ++j)
            atomicAdd(&dst[(dt * 4 + i) * HDIM + et * 4 + j], kvacc[i * 4 + j]);
}

// ---------------------------------------------------------------------------
// Kernel 2: Weff[b][c][o] = (1/NP) * sum_d Wq[c][h][d] * kv[b][h][d][e],
// where o = e*4 + h (the reference's '->bxyeh' + reshape channel order).
// Tiny: 4 batches x 16384 entries x 32 MACs.
// grid = 64, block = 256, 4 entries/thread.
// ---------------------------------------------------------------------------
__global__ __launch_bounds__(256) void weff_kernel(const float* __restrict__ Wq,
                                                   const float* __restrict__ kv_g,
                                                   float* __restrict__ Weff) {
    const int b = blockIdx.x >> 4;
    const int part = blockIdx.x & 15;
    const int base = part * 1024 + threadIdx.x * 4;
    const int c = base >> 7;
    const int o0 = base & 127;
    const float* kvb = kv_g + b * (NHEADS * HDIM * HDIM);
#pragma unroll
    for (int n = 0; n < 4; ++n) {
        const int o = o0 + n;
        const int hh = o & 3;
        const int e = o >> 2;
        float s = 0.f;
#pragma unroll
        for (int dd = 0; dd < HDIM; ++dd)
            s += Wq[c * CH + hh * HDIM + dd] * kvb[hh * (HDIM * HDIM) + dd * HDIM + e];
        Weff[b * (CH * CH) + c * CH + o] = s * INV_NP;
    }
}

// ---------------------------------------------------------------------------
// Kernel 3: out[b][p][o] = sum_c X[b][p][c] * Weff[b][c][o]
// Same register-tiled fp32 GEMM as kernel 1, single output matrix.
// grid = 8192 (2048/batch), block = 256, 32 positions/block.
// ---------------------------------------------------------------------------
__global__ __launch_bounds__(256) void out_kernel(const float* __restrict__ X,
                                                  const float* __restrict__ Weff,
                                                  float* __restrict__ out) {
    __shared__ float smem[8192];       // 32 KB: Xs[32][128], Ws[32][128]
    float* Xs = smem;
    float* Ws = smem + 4096;

    const int tid = threadIdx.x;
    const int tx = tid & 31;
    const int ty = tid >> 5;
    const int b = blockIdx.x >> 11;    // 2048 blocks per batch
    const int ptile = (blockIdx.x & 2047) * 32;

    const float* Xp = X + ((size_t)b * HW + ptile) * CH;
    const float* Wb = Weff + b * (CH * CH);

#pragma unroll
    for (int n = 0; n < 4; ++n) {
        const int i4 = tid + n * 256;
        ((float4*)Xs)[i4] = ((const float4*)Xp)[i4];
    }

    float acc[16];
#pragma unroll
    for (int n = 0; n < 16; ++n) acc[n] = 0.f;

    for (int c0 = 0; c0 < CH; c0 += 32) {
        __syncthreads();
#pragma unroll
        for (int n = 0; n < 4; ++n) {
            const int i4 = tid + n * 256;
            ((float4*)Ws)[i4] = ((const float4*)(Wb + c0 * CH))[i4];
        }
        __syncthreads();
#pragma unroll
        for (int c = 0; c < 32; ++c) {
            const float4 w4 = *(const float4*)&Ws[c * CH + tx * 4];
#pragma unroll
            for (int i = 0; i < 4; ++i) {
                const float xi = Xs[(ty * 4 + i) * CH + c0 + c];
                acc[i * 4 + 0] += xi * w4.x;
                acc[i * 4 + 1] += xi * w4.y;
                acc[i * 4 + 2] += xi * w4.z;
                acc[i * 4 + 3] += xi * w4.w;
            }
        }
    }

    float* op = out + ((size_t)b * HW + ptile) * CH;
#pragma unroll
    for (int i = 0; i < 4; ++i) {
        float4 r;
        r.x = acc[i * 4 + 0];
        r.y = acc[i * 4 + 1];
        r.z = acc[i * 4 + 2];
        r.w = acc[i * 4 + 3];
        *(float4*)&op[(ty * 4 + i) * CH + tx * 4] = r;
    }
}

extern "C" void kernel_launch(void* const* d_in, const int* in_sizes, int n_in,
                              void* d_out, int out_size, void* d_ws, size_t ws_size,
                              hipStream_t stream) {
    const float* X     = (const float*)d_in[0];
    const float* Wq    = (const float*)d_in[1];
    const float* Wk    = (const float*)d_in[2];
    const float* Wv    = (const float*)d_in[3];
    const float* gamma = (const float*)d_in[4];
    const float* beta  = (const float*)d_in[5];
    float* out = (float*)d_out;

    float* kv_g = (float*)d_ws;              // [4][4][32][32] = 16384 floats
    float* Weff = (float*)d_ws + 16384;      // [4][128][128]  = 65536 floats

    hipMemsetAsync(kv_g, 0, 16384 * sizeof(float), stream);
    kv_kernel<<<2048, 256, 0, stream>>>(X, Wk, Wv, gamma, beta, kv_g);
    weff_kernel<<<64, 256, 0, stream>>>(Wq, kv_g, Weff);
    out_kernel<<<8192, 256, 0, stream>>>(X, Weff, out);
}

// Round 2
// 307.932 us; speedup vs baseline: 2.0688x; 2.0688x over previous
//
#include <hip/hip_runtime.h>

// Problem constants (B=4, Hs=Ws=256, C=128, n_heads=4, head_dim=32)
#define HW 65536          // Hs*Ws positions per batch
#define CH 128
#define NHEADS 4
#define HDIM 32
#define EPS 1e-5f
#define INV_NP (1.0f / 65536.0f)
#define INV_C (1.0f / 128.0f)

typedef float v4f __attribute__((ext_vector_type(4)));
typedef short v8s __attribute__((ext_vector_type(8)));
typedef unsigned int v2u __attribute__((ext_vector_type(2)));
typedef unsigned int v4u __attribute__((ext_vector_type(4)));

__device__ __forceinline__ ushort f2bf(float f) {
    uint u = __float_as_uint(f);
    return (ushort)((u + 0x7FFFu + ((u >> 16) & 1u)) >> 16);
}

#define MFMA(a, b, c) __builtin_amdgcn_mfma_f32_16x16x32_bf16((a), (b), (c), 0, 0, 0)

// ---------------------------------------------------------------------------
// Kernel 1 (kv): per block, transpose+convert Wk/Wv into LDS bf16 once, then
// stream 8 tiles of 64 positions: X fp32 -> bf16 LDS, MFMA GEMM for k,v
// (wave0/2 = k, wave1/3 = v; each wave 32 pos x 128 cols), LayerNorm in fp32
// from C-fragments, stage normalized k,v transposed ([ch][pos] bf16), then
// MFMA outer-product k^T·v per head (wave w = head w) into persistent
// accumulators; atomicAdd to kv_g at the end.
//
// LDS (ushort units): WkT chunks[4][128][32] @0, WvT @16384,
//   Xs chunks[4][64][32] @32768 (8192) -- reused as ksmT[128][32]@32768 +
//   vsmT[128][32]@36864 during outer-product rounds. Total 80 KB -> 2 blk/CU.
// grid = 512 (128 blocks/batch, 512 consecutive positions each), block = 256.
// ---------------------------------------------------------------------------
#define LDS_WKT 0
#define LDS_WVT 16384
#define LDS_XS  32768
#define LDS_KST 32768
#define LDS_VST 36864

__global__ __launch_bounds__(256, 2) void kv_kernel(const float* __restrict__ X,
                                                    const float* __restrict__ Wk,
                                                    const float* __restrict__ Wv,
                                                    const float* __restrict__ gamma,
                                                    const float* __restrict__ beta,
                                                    float* __restrict__ kv_g) {
    __shared__ ushort lds[40960];
    const int tid  = threadIdx.x;
    const int lane = tid & 63;
    const int w    = tid >> 6;        // wave id 0..3
    const int q    = lane >> 4;       // quad 0..3
    const int ln   = lane & 15;
    const int phalf = w >> 1;         // position half (0: pos 0-31, 1: 32-63)
    const int isv   = w & 1;          // 0: k-matrix, 1: v-matrix
    const int WTb   = isv ? LDS_WVT : LDS_WKT;

    const int batch  = blockIdx.x >> 7;      // 128 blocks per batch
    const int blocal = blockIdx.x & 127;
    const float* Xb = X + ((size_t)batch * HW + (size_t)blocal * 512) * CH;

    // ---- W transpose + fp32->bf16 into LDS (one-time) ----
    // element idx*4 = c*128 + j0 ; write WT[j][c] chunked [c/32][j][c%32]
#pragma unroll
    for (int n = 0; n < 16; ++n) {
        const int idx = n * 256 + tid;
        const int c  = idx >> 5;
        const int j0 = (idx & 31) << 2;
        const float4 a = ((const float4*)Wk)[idx];
        const float4 b = ((const float4*)Wv)[idx];
        const int cb = (c >> 5) * 4096 + (c & 31);
        lds[LDS_WKT + cb + (j0 + 0) * 32] = f2bf(a.x);
        lds[LDS_WKT + cb + (j0 + 1) * 32] = f2bf(a.y);
        lds[LDS_WKT + cb + (j0 + 2) * 32] = f2bf(a.z);
        lds[LDS_WKT + cb + (j0 + 3) * 32] = f2bf(a.w);
        lds[LDS_WVT + cb + (j0 + 0) * 32] = f2bf(b.x);
        lds[LDS_WVT + cb + (j0 + 1) * 32] = f2bf(b.y);
        lds[LDS_WVT + cb + (j0 + 2) * 32] = f2bf(b.z);
        lds[LDS_WVT + cb + (j0 + 3) * 32] = f2bf(b.w);
    }

    // gamma/beta per lane: channel = ct*16 + ln (same params for k and v!)
    float g8[8], be8[8];
#pragma unroll
    for (int ct = 0; ct < 8; ++ct) {
        g8[ct]  = gamma[ct * 16 + ln];
        be8[ct] = beta[ct * 16 + ln];
    }

    // persistent kv accumulators (head = w): [dt][et] 16x16 tiles of [32d][32e]
    v4f kv00 = {0.f, 0.f, 0.f, 0.f}, kv01 = kv00, kv10 = kv00, kv11 = kv00;

    // X prefetch registers: 8 float4 per thread = 64x128 fp32 tile
    float4 xp[8];
#pragma unroll
    for (int n = 0; n < 8; ++n) xp[n] = ((const float4*)Xb)[n * 256 + tid];

    for (int t = 0; t < 8; ++t) {
        __syncthreads();   // staging reads of prev tile done; Xs area free
        // ds_write X tile (cvt to bf16, chunked layout)
#pragma unroll
        for (int n = 0; n < 8; ++n) {
            const int idx = n * 256 + tid;
            const int p  = idx >> 5;
            const int c0 = (idx & 31) << 2;
            const int off = LDS_XS + ((c0 >> 5) << 11) + (p << 5) + (c0 & 31);
            v2u pk;
            pk.x = (uint)f2bf(xp[n].x) | ((uint)f2bf(xp[n].y) << 16);
            pk.y = (uint)f2bf(xp[n].z) | ((uint)f2bf(xp[n].w) << 16);
            *(v2u*)(lds + off) = pk;
        }
        if (t < 7) {
            const float4* src = (const float4*)(Xb + (size_t)(t + 1) * 64 * CH);
#pragma unroll
            for (int n = 0; n < 8; ++n) xp[n] = src[n * 256 + tid];
        }
        __syncthreads();   // Xs ready

        // ---- GEMM: this wave's 32 positions x 128 cols of k or v ----
        v4f acc[2][8];
#pragma unroll
        for (int rt = 0; rt < 2; ++rt)
#pragma unroll
            for (int ct = 0; ct < 8; ++ct) acc[rt][ct] = kv00 * 0.f;
#pragma unroll
        for (int ks = 0; ks < 4; ++ks) {
            const v8s A0 = *(const v8s*)(lds + LDS_XS + ks * 2048 + (phalf * 32 + ln) * 32 + q * 8);
            const v8s A1 = *(const v8s*)(lds + LDS_XS + ks * 2048 + (phalf * 32 + 16 + ln) * 32 + q * 8);
#pragma unroll
            for (int ct = 0; ct < 8; ++ct) {
                const v8s B = *(const v8s*)(lds + WTb + ks * 4096 + (ct * 16 + ln) * 32 + q * 8);
                acc[0][ct] = MFMA(A0, B, acc[0][ct]);
                acc[1][ct] = MFMA(A1, B, acc[1][ct]);
            }
        }

        // ---- LayerNorm stats (fp32): row sums over the 128 cols ----
        float mu[2][4], rs[2][4];
#pragma unroll
        for (int rt = 0; rt < 2; ++rt) {
#pragma unroll
            for (int r = 0; r < 4; ++r) {
                float s = 0.f, sq = 0.f;
#pragma unroll
                for (int ct = 0; ct < 8; ++ct) {
                    const float v = acc[rt][ct][r];
                    s += v;
                    sq += v * v;
                }
#pragma unroll
                for (int m = 1; m <= 8; m <<= 1) {
                    s  += __shfl_xor(s, m);
                    sq += __shfl_xor(sq, m);
                }
                const float m1 = s * INV_C;
                const float var = sq * INV_C - m1 * m1;
                mu[rt][r] = m1;
                rs[rt][r] = 1.0f / sqrtf(var + EPS);
            }
        }

        __syncthreads();   // all waves done reading Xs; staging may overwrite

        // ---- two rounds of 32 positions: stage normalized k,v transposed,
        //      then MFMA outer product per head ----
#pragma unroll
        for (int rnd = 0; rnd < 2; ++rnd) {
            if (phalf == rnd) {
                const int base = (isv ? LDS_VST : LDS_KST);
#pragma unroll
                for (int ct = 0; ct < 8; ++ct) {
                    const int chb = base + (ct * 16 + ln) * 32;
#pragma unroll
                    for (int rt = 0; rt < 2; ++rt) {
#pragma unroll
                        for (int r = 0; r < 4; r += 2) {
                            const float v0 = (acc[rt][ct][r] - mu[rt][r]) * rs[rt][r] * g8[ct] + be8[ct];
                            const float v1 = (acc[rt][ct][r + 1] - mu[rt][r + 1]) * rs[rt][r + 1] * g8[ct] + be8[ct];
                            const int p32 = rt * 16 + q * 4 + r;
                            *(uint*)(lds + chb + p32) = (uint)f2bf(v0) | ((uint)f2bf(v1) << 16);
                        }
                    }
                }
            }
            __syncthreads();   // staging ready
            {
                const v8s Ad0 = *(const v8s*)(lds + LDS_KST + (w * 32 + ln) * 32 + q * 8);
                const v8s Ad1 = *(const v8s*)(lds + LDS_KST + (w * 32 + 16 + ln) * 32 + q * 8);
                const v8s Be0 = *(const v8s*)(lds + LDS_VST + (w * 32 + ln) * 32 + q * 8);
                const v8s Be1 = *(const v8s*)(lds + LDS_VST + (w * 32 + 16 + ln) * 32 + q * 8);
                kv00 = MFMA(Ad0, Be0, kv00);
                kv01 = MFMA(Ad0, Be1, kv01);
                kv10 = MFMA(Ad1, Be0, kv10);
                kv11 = MFMA(Ad1, Be1, kv11);
            }
            __syncthreads();   // outer reads done before next staging write
        }
    }

    // ---- epilogue: atomicAdd the per-block kv partial ----
    float* dst = kv_g + (batch * NHEADS + w) * (HDIM * HDIM);
#pragma unroll
    for (int dt = 0; dt < 2; ++dt)
#pragma unroll
        for (int et = 0; et < 2; ++et) {
            const v4f f = dt == 0 ? (et == 0 ? kv00 : kv01) : (et == 0 ? kv10 : kv11);
#pragma unroll
            for (int r = 0; r < 4; ++r) {
                const int d = dt * 16 + q * 4 + r;
                const int e = et * 16 + ln;
                atomicAdd(&dst[d * HDIM + e], f[r]);
            }
        }
}

// ---------------------------------------------------------------------------
// Kernel 2: WeffT[b][o][c] = bf16( (1/NP) * sum_d Wq[c][h][d]*kv[b][h][d][e] ),
// o = e*4 + h (reference's '->bxyeh' + reshape order). grid 64, block 256.
// ---------------------------------------------------------------------------
__global__ __launch_bounds__(256) void weff_kernel(const float* __restrict__ Wq,
                                                   const float* __restrict__ kv_g,
                                                   ushort* __restrict__ WeffT) {
    const int b = blockIdx.x >> 4;
    const int part = blockIdx.x & 15;
    const int base = part * 1024 + threadIdx.x * 4;
    const int c = base >> 7;
    const int o0 = base & 127;
    const float* kvb = kv_g + b * (NHEADS * HDIM * HDIM);
#pragma unroll
    for (int n = 0; n < 4; ++n) {
        const int o = o0 + n;
        const int h = o & 3;
        const int e = o >> 2;
        float s = 0.f;
#pragma unroll
        for (int d = 0; d < HDIM; ++d)
            s += Wq[c * CH + h * HDIM + d] * kvb[h * (HDIM * HDIM) + d * HDIM + e];
        WeffT[b * (CH * CH) + o * CH + c] = f2bf(s * INV_NP);
    }
}

// ---------------------------------------------------------------------------
// Kernel 3 (out): WeffT bf16 resident in LDS (chunked), X tiles double-
// buffered bf16, MFMA GEMM out[p][o] = sum_c X[p][c]*Weff[c][o], fp32 stores.
// LDS: WeffT chunks[4][128][32] @0 (16384), Xs dbuf @16384 + 8192*buf.
// 64 KB -> 2 blk/CU. grid = 1024 (256/batch, 256 pos each), block = 256.
// ---------------------------------------------------------------------------
__global__ __launch_bounds__(256, 2) void out_kernel(const float* __restrict__ X,
                                                     const ushort* __restrict__ WeffT,
                                                     float* __restrict__ out) {
    __shared__ ushort lds[32768];
    const int tid  = threadIdx.x;
    const int lane = tid & 63;
    const int w    = tid >> 6;
    const int q    = lane >> 4;
    const int ln   = lane & 15;
    const int phalf = w >> 1;
    const int chalf = w & 1;

    const int batch  = blockIdx.x >> 8;      // 256 blocks per batch
    const int blocal = blockIdx.x & 255;
    const size_t p0 = (size_t)batch * HW + (size_t)blocal * 256;
    const float* Xb = X + p0 * CH;

    // X tile 0 prefetch
    float4 xp[8];
#pragma unroll
    for (int n = 0; n < 8; ++n) xp[n] = ((const float4*)Xb)[n * 256 + tid];

    // stage WeffT (already bf16) into chunked LDS
    const ushort* Wt = WeffT + batch * (CH * CH);
#pragma unroll
    for (int n = 0; n < 8; ++n) {
        const int idx = n * 256 + tid;
        const int o  = idx >> 4;
        const int c0 = (idx & 15) << 3;
        const v4u vv = ((const v4u*)Wt)[idx];
        *(v4u*)(lds + (c0 >> 5) * 4096 + o * 32 + (c0 & 31)) = vv;
    }

    // write X tile 0 into buf 0
#pragma unroll
    for (int n = 0; n < 8; ++n) {
        const int idx = n * 256 + tid;
        const int p  = idx >> 5;
        const int c0 = (idx & 31) << 2;
        v2u pk;
        pk.x = (uint)f2bf(xp[n].x) | ((uint)f2bf(xp[n].y) << 16);
        pk.y = (uint)f2bf(xp[n].z) | ((uint)f2bf(xp[n].w) << 16);
        *(v2u*)(lds + 16384 + ((c0 >> 5) << 11) + (p << 5) + (c0 & 31)) = pk;
    }
    __syncthreads();

    for (int t = 0; t < 4; ++t) {
        if (t < 3) {
            const float4* src = (const float4*)(Xb + (size_t)(t + 1) * 64 * CH);
#pragma unroll
            for (int n = 0; n < 8; ++n) xp[n] = src[n * 256 + tid];
        }
        const int xsb = 16384 + (t & 1) * 8192;

        v4f acc[2][4];
#pragma unroll
        for (int rt = 0; rt < 2; ++rt)
#pragma unroll
            for (int ct = 0; ct < 4; ++ct) acc[rt][ct] = (v4f){0.f, 0.f, 0.f, 0.f};
#pragma unroll
        for (int ks = 0; ks < 4; ++ks) {
            const v8s A0 = *(const v8s*)(lds + xsb + ks * 2048 + (phalf * 32 + ln) * 32 + q * 8);
            const v8s A1 = *(const v8s*)(lds + xsb + ks * 2048 + (phalf * 32 + 16 + ln) * 32 + q * 8);
#pragma unroll
            for (int ct = 0; ct < 4; ++ct) {
                const v8s B = *(const v8s*)(lds + ks * 4096 + (chalf * 64 + ct * 16 + ln) * 32 + q * 8);
                acc[0][ct] = MFMA(A0, B, acc[0][ct]);
                acc[1][ct] = MFMA(A1, B, acc[1][ct]);
            }
        }

        // write next X tile into the other buffer (safe: its readers passed
        // the barrier at the end of tile t-1)
        if (t < 3) {
            const int xsb2 = 16384 + ((t + 1) & 1) * 8192;
#pragma unroll
            for (int n = 0; n < 8; ++n) {
                const int idx = n * 256 + tid;
                const int p  = idx >> 5;
                const int c0 = (idx & 31) << 2;
                v2u pk;
                pk.x = (uint)f2bf(xp[n].x) | ((uint)f2bf(xp[n].y) << 16);
                pk.y = (uint)f2bf(xp[n].z) | ((uint)f2bf(xp[n].w) << 16);
                *(v2u*)(lds + xsb2 + ((c0 >> 5) << 11) + (p << 5) + (c0 & 31)) = pk;
            }
        }

        // fp32 stores
        float* op = out + (p0 + t * 64) * CH;
#pragma unroll
        for (int rt = 0; rt < 2; ++rt)
#pragma unroll
            for (int ct = 0; ct < 4; ++ct)
#pragma unroll
                for (int r = 0; r < 4; ++r) {
                    const int p = phalf * 32 + rt * 16 + q * 4 + r;
                    const int col = chalf * 64 + ct * 16 + ln;
                    op[p * CH + col] = acc[rt][ct][r];
                }
        __syncthreads();
    }
}

extern "C" void kernel_launch(void* const* d_in, const int* in_sizes, int n_in,
                              void* d_out, int out_size, void* d_ws, size_t ws_size,
                              hipStream_t stream) {
    const float* X     = (const float*)d_in[0];
    const float* Wq    = (const float*)d_in[1];
    const float* Wk    = (const float*)d_in[2];
    const float* Wv    = (const float*)d_in[3];
    const float* gamma = (const float*)d_in[4];
    const float* beta  = (const float*)d_in[5];
    float* out = (float*)d_out;

    float*  kv_g  = (float*)d_ws;                       // [4][4][32][32] fp32, 64 KB
    ushort* WeffT = (ushort*)((char*)d_ws + 65536);     // [4][128][128] bf16, 128 KB

    hipMemsetAsync(kv_g, 0, 16384 * sizeof(float), stream);
    kv_kernel<<<512, 256, 0, stream>>>(X, Wk, Wv, gamma, beta, kv_g);
    weff_kernel<<<64, 256, 0, stream>>>(Wq, kv_g, WeffT);
    out_kernel<<<1024, 256, 0, stream>>>(X, WeffT, out);
}

// Round 3
// 304.633 us; speedup vs baseline: 2.0912x; 1.0108x over previous
//
#include <hip/hip_runtime.h>

// Problem constants (B=4, Hs=Ws=256, C=128, n_heads=4, head_dim=32)
#define HW 65536          // Hs*Ws positions per batch
#define CH 128
#define NHEADS 4
#define HDIM 32
#define EPS 1e-5f
#define INV_NP (1.0f / 65536.0f)
#define INV_C (1.0f / 128.0f)

typedef float v4f __attribute__((ext_vector_type(4)));
typedef short v8s __attribute__((ext_vector_type(8)));
typedef unsigned int v4u __attribute__((ext_vector_type(4)));

__device__ __forceinline__ ushort f2bf(float f) {
    uint u = __float_as_uint(f);
    return (ushort)((u + 0x7FFFu + ((u >> 16) & 1u)) >> 16);
}

__device__ __forceinline__ v8s pack8(float4 a, float4 b) {
    v8s r;
    r[0] = (short)f2bf(a.x); r[1] = (short)f2bf(a.y);
    r[2] = (short)f2bf(a.z); r[3] = (short)f2bf(a.w);
    r[4] = (short)f2bf(b.x); r[5] = (short)f2bf(b.y);
    r[6] = (short)f2bf(b.z); r[7] = (short)f2bf(b.w);
    return r;
}

#define MFMA(a, b, c) __builtin_amdgcn_mfma_f32_16x16x32_bf16((a), (b), (c), 0, 0, 0)

// Swizzled B-matrix image layout (bank-conflict-free MFMA B reads):
//   element (row j in 0..127, k in 0..127) stored at ushort index
//   j*128 + (((k>>3) + j) & 15)*8 + (k&7)
// Read of fragment (row, kb=ks*4+q) => 16B at j*128 + ((kb+j)&15)*8:
// word%32 = 4*((kb+j)&7)+i -> within an 8-lane group (q fixed, ln consecutive)
// all 8 lanes hit distinct bank quads. Linear copy HBM->LDS is stride-1.

// ---------------------------------------------------------------------------
// prep: build swizzled bf16 WkT/WvT images; zero the kv accumulator.
// grid = 32, block = 256.
// ---------------------------------------------------------------------------
__global__ __launch_bounds__(256) void prep_kernel(const float* __restrict__ Wk,
                                                   const float* __restrict__ Wv,
                                                   ushort* __restrict__ SWkT,
                                                   ushort* __restrict__ SWvT,
                                                   float* __restrict__ kv_g) {
    const int t = blockIdx.x * 256 + threadIdx.x;   // 0..8191
    kv_g[t] = 0.f;
    kv_g[t + 8192] = 0.f;
#pragma unroll
    for (int i = 0; i < 2; ++i) {
        const int e = i * 8192 + t;          // e = c*128 + row
        const int c = e >> 7;
        const int row = e & 127;
        const int dst = row * 128 + (((c >> 3) + row) & 15) * 8 + (c & 7);
        SWkT[dst] = f2bf(Wk[e]);
        SWvT[dst] = f2bf(Wv[e]);
    }
}

// ---------------------------------------------------------------------------
// Kernel 1 (kv): stage swizzled WkT/WvT into LDS (linear copy). Per 64-pos
// tile: A-fragments of X loaded straight from global (fp32->bf16 in regs),
// MFMA GEMM for k,v (wave0/2=k halves, wave1/3=v), LN stats via shfl,
// normalized k,v staged transposed (rotated layout) and reduced into per-head
// kv accumulators by MFMA; atomicAdd at the end.
// LDS: SWkT[16384] @0, SWvT @16384, kst[4096] @32768, vst[4096] @36864 =80KB.
// grid = 512 (128/batch, 512 pos each), block = 256.
// ---------------------------------------------------------------------------
__global__ __launch_bounds__(256, 2) void kv_kernel(const float* __restrict__ X,
                                                    const ushort* __restrict__ SWkT,
                                                    const ushort* __restrict__ SWvT,
                                                    const float* __restrict__ gamma,
                                                    const float* __restrict__ beta,
                                                    float* __restrict__ kv_g) {
    __shared__ ushort lds[40960];
    const int tid  = threadIdx.x;
    const int lane = tid & 63;
    const int w    = tid >> 6;
    const int q    = lane >> 4;
    const int ln   = lane & 15;
    const int phalf = w >> 1;         // which 32-pos half of the 64-pos tile
    const int isv   = w & 1;          // 0: k, 1: v
    const int Wb    = isv ? 16384 : 0;

    const int batch  = blockIdx.x >> 7;
    const int blocal = blockIdx.x & 127;
    const float* Xb = X + ((size_t)batch * HW + (size_t)blocal * 512) * CH;

    // linear (conflict-free) staging of the swizzled W images
    {
        const v4u* sk = (const v4u*)SWkT;
        const v4u* sv = (const v4u*)SWvT;
        v4u* dk = (v4u*)lds;
        v4u* dv = (v4u*)(lds + 16384);
#pragma unroll
        for (int n = 0; n < 8; ++n) {
            dk[n * 256 + tid] = sk[n * 256 + tid];
            dv[n * 256 + tid] = sv[n * 256 + tid];
        }
    }

    float g8[8], be8[8];
#pragma unroll
    for (int ct = 0; ct < 8; ++ct) {
        g8[ct]  = gamma[ct * 16 + ln];
        be8[ct] = beta[ct * 16 + ln];
    }

    v4f kv00 = {0.f, 0.f, 0.f, 0.f}, kv01 = kv00, kv10 = kv00, kv11 = kv00;

    __syncthreads();

    for (int t = 0; t < 8; ++t) {
        const float* Xt = Xb + (size_t)t * 64 * CH;

        // ---- A-fragments from global (this wave's 32 rows) ----
        float4 xa[4][4];
#pragma unroll
        for (int ks = 0; ks < 4; ++ks) {
            const float* b0 = Xt + (phalf * 32 + ln) * CH + ks * 32 + q * 8;
            xa[ks][0] = *(const float4*)b0;
            xa[ks][1] = *(const float4*)(b0 + 4);
            xa[ks][2] = *(const float4*)(b0 + 16 * CH);
            xa[ks][3] = *(const float4*)(b0 + 16 * CH + 4);
        }
        v8s A0[4], A1[4];
#pragma unroll
        for (int ks = 0; ks < 4; ++ks) {
            A0[ks] = pack8(xa[ks][0], xa[ks][1]);
            A1[ks] = pack8(xa[ks][2], xa[ks][3]);
        }

        // ---- GEMM: 32 pos x 128 cols of k or v ----
        v4f acc[2][8];
#pragma unroll
        for (int rt = 0; rt < 2; ++rt)
#pragma unroll
            for (int ct = 0; ct < 8; ++ct) acc[rt][ct] = (v4f){0.f, 0.f, 0.f, 0.f};
#pragma unroll
        for (int ks = 0; ks < 4; ++ks) {
#pragma unroll
            for (int ct = 0; ct < 8; ++ct) {
                const int row = ct * 16 + ln;
                const v8s B = *(const v8s*)(lds + Wb + row * 128 + (((ks * 4 + q) + row) & 15) * 8);
                acc[0][ct] = MFMA(A0[ks], B, acc[0][ct]);
                acc[1][ct] = MFMA(A1[ks], B, acc[1][ct]);
            }
        }

        // ---- LayerNorm stats across the 128 cols (fp32, shfl reduce) ----
        float mu[2][4], rs[2][4];
#pragma unroll
        for (int rt = 0; rt < 2; ++rt) {
#pragma unroll
            for (int r = 0; r < 4; ++r) {
                float s = 0.f, sq = 0.f;
#pragma unroll
                for (int ct = 0; ct < 8; ++ct) {
                    const float v = acc[rt][ct][r];
                    s += v;
                    sq += v * v;
                }
#pragma unroll
                for (int m = 1; m <= 8; m <<= 1) {
                    s  += __shfl_xor(s, m);
                    sq += __shfl_xor(sq, m);
                }
                const float m1 = s * INV_C;
                const float var = sq * INV_C - m1 * m1;
                mu[rt][r] = m1;
                rs[rt][r] = 1.0f / sqrtf(var + EPS);
            }
        }

        // ---- two 32-pos rounds: stage normalized k,v transposed, MFMA outer ----
#pragma unroll
        for (int rnd = 0; rnd < 2; ++rnd) {
            if (phalf == rnd) {
                const int base = 32768 + isv * 4096;
#pragma unroll
                for (int ct = 0; ct < 8; ++ct) {
                    const int chn = ct * 16 + ln;
#pragma unroll
                    for (int rt = 0; rt < 2; ++rt) {
#pragma unroll
                        for (int r = 0; r < 4; r += 2) {
                            const float v0 = (acc[rt][ct][r] - mu[rt][r]) * rs[rt][r] * g8[ct] + be8[ct];
                            const float v1 = (acc[rt][ct][r + 1] - mu[rt][r + 1]) * rs[rt][r + 1] * g8[ct] + be8[ct];
                            const int p32 = rt * 16 + q * 4 + r;
                            const int off = base + chn * 32 + (((p32 >> 3) + chn) & 3) * 8 + (p32 & 7);
                            *(uint*)(lds + off) = (uint)f2bf(v0) | ((uint)f2bf(v1) << 16);
                        }
                    }
                }
            }
            __syncthreads();
            {
                const int r0 = w * 32 + ln;
                const int r1 = r0 + 16;
                const v8s Ad0 = *(const v8s*)(lds + 32768 + r0 * 32 + ((q + r0) & 3) * 8);
                const v8s Ad1 = *(const v8s*)(lds + 32768 + r1 * 32 + ((q + r1) & 3) * 8);
                const v8s Be0 = *(const v8s*)(lds + 36864 + r0 * 32 + ((q + r0) & 3) * 8);
                const v8s Be1 = *(const v8s*)(lds + 36864 + r1 * 32 + ((q + r1) & 3) * 8);
                kv00 = MFMA(Ad0, Be0, kv00);
                kv01 = MFMA(Ad0, Be1, kv01);
                kv10 = MFMA(Ad1, Be0, kv10);
                kv11 = MFMA(Ad1, Be1, kv11);
            }
            __syncthreads();
        }
    }

    float* dst = kv_g + (batch * NHEADS + w) * (HDIM * HDIM);
#pragma unroll
    for (int dt = 0; dt < 2; ++dt)
#pragma unroll
        for (int et = 0; et < 2; ++et) {
            const v4f f = dt == 0 ? (et == 0 ? kv00 : kv01) : (et == 0 ? kv10 : kv11);
#pragma unroll
            for (int r = 0; r < 4; ++r) {
                const int d = dt * 16 + q * 4 + r;
                const int e = et * 16 + ln;
                atomicAdd(&dst[d * HDIM + e], f[r]);
            }
        }
}

// ---------------------------------------------------------------------------
// Kernel 2: SWeffT = swizzled bf16 image of Weff^T where
// Weff[c][o] = (1/NP) sum_d Wq[c][h][d] kv[b][h][d][e], o = e*4+h.
// grid 64, block 256.
// ---------------------------------------------------------------------------
__global__ __launch_bounds__(256) void weff_kernel(const float* __restrict__ Wq,
                                                   const float* __restrict__ kv_g,
                                                   ushort* __restrict__ SWeffT) {
    const int b = blockIdx.x >> 4;
    const int part = blockIdx.x & 15;
    const int base = part * 1024 + threadIdx.x * 4;
    const int c = base >> 7;
    const int o0 = base & 127;
    const float* kvb = kv_g + b * (NHEADS * HDIM * HDIM);
#pragma unroll
    for (int n = 0; n < 4; ++n) {
        const int o = o0 + n;
        const int h = o & 3;
        const int e = o >> 2;
        float s = 0.f;
#pragma unroll
        for (int d = 0; d < HDIM; ++d)
            s += Wq[c * CH + h * HDIM + d] * kvb[h * (HDIM * HDIM) + d * HDIM + e];
        SWeffT[b * (CH * CH) + o * 128 + (((c >> 3) + o) & 15) * 8 + (c & 7)] = f2bf(s * INV_NP);
    }
}

// ---------------------------------------------------------------------------
// Kernel 3 (out): stage swizzled SWeffT (32 KB LDS, linear copy), then
// barrier-free K-loop: A-fragments of X from global, MFMA, fp32 stores.
// grid = 2048 (512/batch, 2 tiles of 64 pos each), block = 256.
// ---------------------------------------------------------------------------
__global__ __launch_bounds__(256) void out_kernel(const float* __restrict__ X,
                                                  const ushort* __restrict__ SWeffT,
                                                  float* __restrict__ out) {
    __shared__ ushort lds[16384];
    const int tid  = threadIdx.x;
    const int lane = tid & 63;
    const int w    = tid >> 6;
    const int q    = lane >> 4;
    const int ln   = lane & 15;
    const int phalf = w >> 1;
    const int chalf = w & 1;

    const int batch  = blockIdx.x >> 9;
    const int blocal = blockIdx.x & 511;
    const size_t p0 = (size_t)batch * HW + (size_t)blocal * 128;

    {
        const v4u* s = (const v4u*)(SWeffT + batch * (CH * CH));
        v4u* d = (v4u*)lds;
#pragma unroll
        for (int n = 0; n < 8; ++n) d[n * 256 + tid] = s[n * 256 + tid];
    }
    __syncthreads();

    for (int t = 0; t < 2; ++t) {
        const float* Xt = X + (p0 + (size_t)t * 64) * CH;

        float4 xa[4][4];
#pragma unroll
        for (int ks = 0; ks < 4; ++ks) {
            const float* b0 = Xt + (phalf * 32 + ln) * CH + ks * 32 + q * 8;
            xa[ks][0] = *(const float4*)b0;
            xa[ks][1] = *(const float4*)(b0 + 4);
            xa[ks][2] = *(const float4*)(b0 + 16 * CH);
            xa[ks][3] = *(const float4*)(b0 + 16 * CH + 4);
        }
        v8s A0[4], A1[4];
#pragma unroll
        for (int ks = 0; ks < 4; ++ks) {
            A0[ks] = pack8(xa[ks][0], xa[ks][1]);
            A1[ks] = pack8(xa[ks][2], xa[ks][3]);
        }

        v4f acc[2][4];
#pragma unroll
        for (int rt = 0; rt < 2; ++rt)
#pragma unroll
            for (int ct = 0; ct < 4; ++ct) acc[rt][ct] = (v4f){0.f, 0.f, 0.f, 0.f};
#pragma unroll
        for (int ks = 0; ks < 4; ++ks) {
#pragma unroll
            for (int ct = 0; ct < 4; ++ct) {
                const int row = chalf * 64 + ct * 16 + ln;
                const v8s B = *(const v8s*)(lds + row * 128 + (((ks * 4 + q) + row) & 15) * 8);
                acc[0][ct] = MFMA(A0[ks], B, acc[0][ct]);
                acc[1][ct] = MFMA(A1[ks], B, acc[1][ct]);
            }
        }

        float* op = out + (p0 + (size_t)t * 64) * CH;
#pragma unroll
        for (int rt = 0; rt < 2; ++rt)
#pragma unroll
            for (int ct = 0; ct < 4; ++ct)
#pragma unroll
                for (int r = 0; r < 4; ++r) {
                    const int p = phalf * 32 + rt * 16 + q * 4 + r;
                    const int col = chalf * 64 + ct * 16 + ln;
                    op[p * CH + col] = acc[rt][ct][r];
                }
    }
}

extern "C" void kernel_launch(void* const* d_in, const int* in_sizes, int n_in,
                              void* d_out, int out_size, void* d_ws, size_t ws_size,
                              hipStream_t stream) {
    const float* X     = (const float*)d_in[0];
    const float* Wq    = (const float*)d_in[1];
    const float* Wk    = (const float*)d_in[2];
    const float* Wv    = (const float*)d_in[3];
    const float* gamma = (const float*)d_in[4];
    const float* beta  = (const float*)d_in[5];
    float* out = (float*)d_out;

    float*  kv_g   = (float*)d_ws;                       // 64 KB
    ushort* SWkT   = (ushort*)((char*)d_ws + 65536);     // 32 KB
    ushort* SWvT   = (ushort*)((char*)d_ws + 98304);     // 32 KB
    ushort* SWeffT = (ushort*)((char*)d_ws + 131072);    // 128 KB

    prep_kernel<<<32, 256, 0, stream>>>(Wk, Wv, SWkT, SWvT, kv_g);
    kv_kernel<<<512, 256, 0, stream>>>(X, SWkT, SWvT, gamma, beta, kv_g);
    weff_kernel<<<64, 256, 0, stream>>>(Wq, kv_g, SWeffT);
    out_kernel<<<2048, 256, 0, stream>>>(X, SWeffT, out);
}